// Round 1
// baseline (954.712 us; speedup 1.0000x reference)
//
#include <hip/hip_runtime.h>

// PoseTokenizer: tokens[b,n,t] = sum_d x[b, n*6+d] * W[n,d,t] + bias[n,t]
// B=32768, N_PARTS=24, PART_DIM=6, TOKEN_DIM=256. All fp32.
// Write-bound: 805 MB output vs 19 MB input. Roofline ~131 us @ 6.3 TB/s.

#define BATCH     32768
#define NPARTS    24
#define PDIM      6
#define TDIM      256
#define B_TILE    64     // batch rows per block

__global__ __launch_bounds__(256) void
PoseTokenizer_56057913147981_kernel(const float* __restrict__ x,
                                    const float* __restrict__ W,
                                    const float* __restrict__ bias,
                                    float* __restrict__ out) {
    const int n    = blockIdx.y;           // part index 0..23
    const int b0   = blockIdx.x * B_TILE;  // first batch row of this block
    const int quad = threadIdx.x & 63;     // owns t = quad*4 .. quad*4+3
    const int rgrp = threadIdx.x >> 6;     // row group 0..3 (one wave each)
    const int t0   = quad * 4;

    // Preload this part's weight columns and bias: W[n][d][t0..t0+3]
    const float* Wn = W + (size_t)n * PDIM * TDIM;
    float4 w[PDIM];
#pragma unroll
    for (int d = 0; d < PDIM; ++d)
        w[d] = *reinterpret_cast<const float4*>(Wn + d * TDIM + t0);
    const float4 bv = *reinterpret_cast<const float4*>(bias + (size_t)n * TDIM + t0);

    const float* xbase = x + (size_t)b0 * (NPARTS * PDIM) + n * PDIM;

    // Each wave (row group) handles rows rgrp, rgrp+4, ... within the tile.
    for (int r = rgrp; r < B_TILE; r += 4) {
        const float* xr = xbase + (size_t)r * (NPARTS * PDIM);
        // x row base byte offset = (b*144 + n*6)*4 = b*576 + n*24 -> 8B aligned
        float2 x01 = *reinterpret_cast<const float2*>(xr);
        float2 x23 = *reinterpret_cast<const float2*>(xr + 2);
        float2 x45 = *reinterpret_cast<const float2*>(xr + 4);
        const float xv[PDIM] = {x01.x, x01.y, x23.x, x23.y, x45.x, x45.y};

        float4 acc = bv;
#pragma unroll
        for (int d = 0; d < PDIM; ++d) {
            acc.x = fmaf(xv[d], w[d].x, acc.x);
            acc.y = fmaf(xv[d], w[d].y, acc.y);
            acc.z = fmaf(xv[d], w[d].z, acc.z);
            acc.w = fmaf(xv[d], w[d].w, acc.w);
        }

        const size_t b = (size_t)(b0 + r);
        *reinterpret_cast<float4*>(out + b * (NPARTS * TDIM) + (size_t)n * TDIM + t0) = acc;
    }
}

extern "C" void kernel_launch(void* const* d_in, const int* in_sizes, int n_in,
                              void* d_out, int out_size, void* d_ws, size_t ws_size,
                              hipStream_t stream) {
    const float* x    = (const float*)d_in[0];   // [32768, 144]
    const float* W    = (const float*)d_in[1];   // [24, 6, 256]
    const float* bias = (const float*)d_in[2];   // [24, 256]
    float* out        = (float*)d_out;           // [32768, 24, 256]

    dim3 grid(BATCH / B_TILE, NPARTS);           // (512, 24)
    dim3 block(256);
    PoseTokenizer_56057913147981_kernel<<<grid, block, 0, stream>>>(x, W, bias, out);
}